// Round 8
// baseline (118692.896 us; speedup 1.0000x reference)
//
#include <hip/hip_runtime.h>

#define L 64
#define TLEN 200000
#define CH 528                        // divisible by 4 and 8; chunk for replay kernels
#define NCH 379                       // ceil(200000/528); 378*528 = 199584
#define LASTLEN (TLEN - (NCH - 1) * CH)   // 416 (divisible by 8)
#define NEGV -10000.0f
#define STARTT 62
#define STOPT 63

// workspace layout (bytes) — total ~123 KB
#define CKPT_OFF 0                          // float[(NCH+1)*L]  = 97280 B
#define M_OFF ((NCH + 1) * L * 4)           // uchar[NCH*L]      = 24256 B
#define ETAG_OFF (M_OFF + NCH * L)          // int[NCH]          = 1516 B

typedef float f32x4 __attribute__((ext_vector_type(4)));

#define STEP_BARRIER() __asm__ volatile("" ::: "memory")

// wave-wide rotate-by-1 DPP (CDNA keeps the wave_* DPP ctrls; 0x13C = WAVE_ROR1)
#define ROT_CTRL 0x13C
static __device__ __forceinline__ float rot1(float x) {
    return __int_as_float(__builtin_amdgcn_mov_dpp(__float_as_int(x), ROT_CTRL, 0xf, 0xf, true));
}

// ---------------------------------------------------------------------------
// Pass 1: exact sequential forward recurrence (the critical path).
// ONE wave, ZERO LDS ops and ZERO barriers in the hot loop.
//
// Register rotation: lane l holds v[l]. Diagonal relayout of the transition
// matrix, Td[r][l] = T[(l - dir*r) & 63][l], lives in 64 resident VGPRs
// (staged through LDS: ds_read results cannot be rematerialized by the
// register allocator, unlike the const-global loads that produced the
// 52-VGPR remat syndrome of rounds 2-4). Per step:
//   e_r[l] = v[l] + Td[r][l]            (64 independent adds, f32x4/pk)
//   acc    = max(rot1(acc), e_r)        for r = 1..63,0  (63-deep DPP chain)
// The accumulator for tag n starts at lane (n + dir) and walks all 64 lanes,
// collecting exactly RN(v[p] + T[n][p]) for every p; max is exact and
// order-invariant; then vreg = acc + feat — bit-identical to the reference.
// The DPP receive direction (lane l <- l-1 vs l <- l+1) is runtime-detected
// with the SAME ctrl code and folded into dir, so either HW convention is
// correct.
// ---------------------------------------------------------------------------
__global__ __launch_bounds__(64, 1) void k_forward(const float* __restrict__ feats,
                                                   const float* __restrict__ trans,
                                                   float* __restrict__ ckpt) {
    const int l = threadIdx.x;

    // --- detect DPP receive offset: probe = value received by this lane ---
    const int probe = __builtin_amdgcn_mov_dpp(l, ROT_CTRL, 0xf, 0xf, true);
    // receives lower neighbor (l-1) => values move UP => dir = +1
    const int dir = (probe == ((l - 1) & 63)) ? 1 : -1;

    // --- stage Td via LDS (padded transpose: row l = this lane's column) ---
    __shared__ __align__(16) float TdT[L * 68];
    for (int j = 0; j < L; ++j) {
        const float val = trans[j * L + l];          // coalesced
        const int r = (dir * (l - j)) & 63;          // (l - dir*r) & 63 == j
        TdT[l * 68 + r] = val;
    }
    STEP_BARRIER();  // single wave: in-order DS pipe; lane l reads only row l

    f32x4 tdq[16];
#pragma unroll
    for (int k = 0; k < 16; ++k)
        tdq[k] = *reinterpret_cast<const f32x4*>(&TdT[l * 68 + 4 * k]);
    // tdq[k][c] = Td[4k+c][l]

    float vreg = (l == STARTT) ? 0.0f : NEGV;  // v_{-1}

    float fc[4];
#pragma unroll
    for (int j = 0; j < 4; ++j) fc[j] = feats[j * L + l];

    int nextck = 0, cidx = 0;
    for (int tb = 0; tb < TLEN; tb += 4) {   // 200000 % 4 == 0
        if (tb == nextck) {                  // uniform branch
            ckpt[cidx * L + l] = vreg;       // v_{tb-1}, coalesced, off-chain
            nextck += CH;
            ++cidx;
        }
        float fn_[4];
        const bool more = (tb + 4) < TLEN;
        if (more) {
#pragma unroll
            for (int j = 0; j < 4; ++j) fn_[j] = feats[(tb + 4 + j) * L + l];
        }
#pragma unroll
        for (int j = 0; j < 4; ++j) {
            const f32x4 v4 = {vreg, vreg, vreg, vreg};
            f32x4 e[16];
#pragma unroll
            for (int k = 0; k < 16; ++k) e[k] = v4 + tdq[k];  // e_r, r = 4k+c

            float acc = e[0][1];             // r = 1
#pragma unroll
            for (int rr = 2; rr < 65; ++rr) {
                const int r = rr & 63;       // 2..63, then 0 (final alignment n=l)
                acc = fmaxf(rot1(acc), e[r >> 2][r & 3]);
            }
            vreg = acc + fc[j];              // v_t[l]
        }
        if (more) {
#pragma unroll
            for (int j = 0; j < 4; ++j) fc[j] = fn_[j];
        }
    }
    ckpt[NCH * L + l] = vreg;  // v_{T-1}
}

// ---------------------------------------------------------------------------
// helpers for the replay kernels (off the critical path, ~1 ms total)
// ---------------------------------------------------------------------------
__device__ __forceinline__ void load_trow(const float* __restrict__ trans, int n, float* trow) {
#pragma unroll
    for (int i = 0; i < 16; ++i) {
        const f32x4 q = reinterpret_cast<const f32x4*>(trans)[n * 16 + i];
        trow[4 * i + 0] = q.x;
        trow[4 * i + 1] = q.y;
        trow[4 * i + 2] = q.z;
        trow[4 * i + 3] = q.w;
    }
}

// Bit-exact chunk replay from checkpoint; records backpointers into LDS.
// Single wave per block; in-order DS pipe makes ds_write->ds_read safe with
// only a compiler barrier. Argmax is an in-order strictly-greater scan =>
// first-max, matching jnp.argmax; v matches k_forward bit-for-bit (max is
// order-invariant, +feat monotone-exact).
__device__ __forceinline__ void replay_chunk(const float* __restrict__ feats,
                                             const float* __restrict__ ckpt,
                                             const float* trow, float* vsh,
                                             unsigned char* bpl, int c, int len, int n) {
    float vreg = ckpt[c * L + n];
    vsh[n] = vreg;
    STEP_BARRIER();
    const int base = c * CH;

    float fc[8];
#pragma unroll
    for (int j = 0; j < 8; ++j) fc[j] = feats[(base + j) * L + n];

    for (int sb = 0; sb < len; sb += 8) {
        float fn_[8];
        const bool more = (sb + 8) < len;
        if (more) {
#pragma unroll
            for (int j = 0; j < 8; ++j) fn_[j] = feats[(base + sb + 8 + j) * L + n];
        }
#pragma unroll
        for (int j = 0; j < 8; ++j) {
            float mc[4];
            int ic[4];
#pragma unroll
            for (int g = 0; g < 4; ++g) {
                float m = -INFINITY;
                int idx = g * 16;
#pragma unroll
                for (int r = 0; r < 4; ++r) {
                    const int pb = g * 16 + r * 4;
                    const f32x4 vv = *reinterpret_cast<const f32x4*>(vsh + pb);
                    const float a = vv.x + trow[pb + 0];
                    const float b = vv.y + trow[pb + 1];
                    const float cc = vv.z + trow[pb + 2];
                    const float d = vv.w + trow[pb + 3];
                    if (a > m)  { m = a;  idx = pb + 0; }
                    if (b > m)  { m = b;  idx = pb + 1; }
                    if (cc > m) { m = cc; idx = pb + 2; }
                    if (d > m)  { m = d;  idx = pb + 3; }
                }
                mc[g] = m;
                ic[g] = idx;
            }
            float m = mc[0];
            int idx = ic[0];
            if (mc[1] > m) { m = mc[1]; idx = ic[1]; }
            if (mc[2] > m) { m = mc[2]; idx = ic[2]; }
            if (mc[3] > m) { m = mc[3]; idx = ic[3]; }

            vreg = m + fc[j];
            bpl[(sb + j) * L + n] = (unsigned char)idx;
            vsh[n] = vreg;
            STEP_BARRIER();
        }
        if (more) {
#pragma unroll
            for (int j = 0; j < 8; ++j) fc[j] = fn_[j];
        }
    }
}

// ---------------------------------------------------------------------------
// Pass 2: per-chunk bit-exact replay -> backpointers -> 64-entry chunk map.
// M[c*64+e] = tag at (c*CH - 1) given tag e at the last step of chunk c.
// ---------------------------------------------------------------------------
__global__ __launch_bounds__(64, 1) void k_maps(const float* __restrict__ feats,
                                                const float* __restrict__ trans,
                                                const float* __restrict__ ckpt,
                                                unsigned char* __restrict__ M) {
    const int c = blockIdx.x;
    const int n = threadIdx.x;
    const int len = (c == NCH - 1) ? LASTLEN : CH;

    __shared__ __align__(16) float vsh[L];
    __shared__ unsigned char bpl[CH * L];

    float trow[L];
    load_trow(trans, n, trow);
    replay_chunk(feats, ckpt, trow, vsh, bpl, c, len, n);
    __syncthreads();

    int tag = n;
    for (int s = len - 1; s >= 0; --s) tag = bpl[s * L + tag];
    M[c * L + n] = (unsigned char)tag;
}

// ---------------------------------------------------------------------------
// Pass 3: terminal argmax (bit-exact score) + back-to-front map composition.
// ---------------------------------------------------------------------------
__global__ __launch_bounds__(64, 1) void k_stitch(const float* __restrict__ trans,
                                                  const float* __restrict__ ckpt,
                                                  const unsigned char* __restrict__ M,
                                                  int* __restrict__ etag,
                                                  float* __restrict__ out) {
    const int n = threadIdx.x;
    __shared__ float tsh[L];
    __shared__ int bsh;
    __shared__ __align__(16) unsigned char msh[NCH * L];

    tsh[n] = ckpt[NCH * L + n] + trans[STOPT * L + n];  // terminal[n]
    __syncthreads();
    if (n == 0) {
        float m = tsh[0];
        int b = 0;
        for (int p = 1; p < L; ++p)
            if (tsh[p] > m) { m = tsh[p]; b = p; }  // first-max, like jnp.argmax
        out[0] = m;   // path_score, bit-exact
        bsh = b;
    }
    __syncthreads();

    for (int i = n; i < (NCH * L) / 4; i += L)
        reinterpret_cast<int*>(msh)[i] = reinterpret_cast<const int*>(M)[i];
    __syncthreads();

    if (n == 0) {
        int carry = bsh;  // tag at t = T-1 = end of chunk NCH-1
        for (int c = NCH - 1; c >= 1; --c) {
            etag[c] = carry;
            carry = msh[c * L + carry];
        }
        etag[0] = carry;
    }
}

// ---------------------------------------------------------------------------
// Pass 4: per-chunk replay again, walk backwards from etag[c], emit path.
// Path written as float32 (harness reads the concatenated output as float).
// ---------------------------------------------------------------------------
__global__ __launch_bounds__(64, 1) void k_emit(const float* __restrict__ feats,
                                                const float* __restrict__ trans,
                                                const float* __restrict__ ckpt,
                                                const int* __restrict__ etag,
                                                float* __restrict__ out) {
    const int c = blockIdx.x;
    const int n = threadIdx.x;
    const int len = (c == NCH - 1) ? LASTLEN : CH;

    __shared__ __align__(16) float vsh[L];
    __shared__ unsigned char bpl[CH * L];
    __shared__ unsigned char plc[CH];

    float trow[L];
    load_trow(trans, n, trow);
    replay_chunk(feats, ckpt, trow, vsh, bpl, c, len, n);
    __syncthreads();

    int tag = etag[c];  // uniform; bpl reads below broadcast (same address)
    for (int s = len - 1; s >= 0; --s) {
        if (n == 0) plc[s] = (unsigned char)tag;
        tag = bpl[s * L + tag];
    }
    __syncthreads();

    for (int i = n; i < len; i += L)
        out[1 + c * CH + i] = (float)plc[i];
}

// ---------------------------------------------------------------------------
extern "C" void kernel_launch(void* const* d_in, const int* in_sizes, int n_in,
                              void* d_out, int out_size, void* d_ws, size_t ws_size,
                              hipStream_t stream) {
    const float* feats = (const float*)d_in[0];   // (1, T, L) fp32
    const float* trans = (const float*)d_in[1];   // (L, L) fp32
    float* out = (float*)d_out;                   // [score, path(T) as float]
    char* ws = (char*)d_ws;
    float* ckpt = (float*)(ws + CKPT_OFF);
    unsigned char* M = (unsigned char*)(ws + M_OFF);
    int* etag = (int*)(ws + ETAG_OFF);

    hipLaunchKernelGGL(k_forward, dim3(1), dim3(64), 0, stream, feats, trans, ckpt);
    hipLaunchKernelGGL(k_maps, dim3(NCH), dim3(64), 0, stream, feats, trans, ckpt, M);
    hipLaunchKernelGGL(k_stitch, dim3(1), dim3(64), 0, stream, trans, ckpt, M, etag, out);
    hipLaunchKernelGGL(k_emit, dim3(NCH), dim3(64), 0, stream, feats, trans, ckpt, etag, out);
}

// Round 9
// 110576.099 us; speedup vs baseline: 1.0734x; 1.0734x over previous
//
#include <hip/hip_runtime.h>

#define L 64
#define TLEN 200000
#define CH 528                        // divisible by 4 and 8; chunk for replay kernels
#define NCH 379                       // ceil(200000/528); 378*528 = 199584
#define LASTLEN (TLEN - (NCH - 1) * CH)   // 416 (divisible by 8)
#define NEGV -10000.0f
#define STARTT 62
#define STOPT 63

// workspace layout (bytes) — total ~123 KB
#define CKPT_OFF 0                          // float[(NCH+1)*L]  = 97280 B
#define M_OFF ((NCH + 1) * L * 4)           // uchar[NCH*L]      = 24256 B
#define ETAG_OFF (M_OFF + NCH * L)          // int[NCH]          = 1516 B

typedef float f32x4 __attribute__((ext_vector_type(4)));

#define STEP_BARRIER() __asm__ volatile("" ::: "memory")

// wave-wide rotate-by-1 DPP (CDNA keeps wave_* DPP ctrls; 0x13C = WAVE_ROR1).
// bound_ctrl=true + full masks => GCNDPPCombine can fuse mov_dpp into the
// consuming v_max_f32 (v_max_f32_dpp), and the compiler owns hazard nops.
#define ROT_CTRL 0x13C
static __device__ __forceinline__ float rot1(float x) {
    return __int_as_float(__builtin_amdgcn_mov_dpp(__float_as_int(x), ROT_CTRL, 0xf, 0xf, true));
}

// ---------------------------------------------------------------------------
// Pass 1: exact sequential forward recurrence (the critical path).
// ONE wave, ZERO LDS ops and ZERO barriers in the hot loop.
//
// Register rotation: lane l holds v[l]. Diagonal relayout Td[r][l] =
// T[(l - dir*r) & 63][l] lives in 64 resident VGPRs (staged through LDS:
// ds_read results cannot be rematerialized — the fix for the rounds-2-4
// global-remat syndrome). Per step, the rotating-accumulator chain:
//   acc = e_1;  acc = max(rot1(acc), e_r)  for r = 2..63,0
// with e_r computed INLINE as (vreg + tdq[r]) — round 8's explicit e[16]
// array forced 64 floats live at chain start and the allocator spilled it
// to scratch (VGPR=72, 140+ ms). Inline adds keep the live set ~80 and give
// the scheduler independent VALU ops to interleave between chain links
// (fills both the DPP hazard slots and the issue slots).
// Result is bit-identical to the reference: each candidate is one fp32 add,
// max is exact/order-invariant, +feat is one add.
// ---------------------------------------------------------------------------
__global__ __launch_bounds__(64, 1) void k_forward(const float* __restrict__ feats,
                                                   const float* __restrict__ trans,
                                                   float* __restrict__ ckpt) {
    const int l = threadIdx.x;

    // --- detect DPP receive offset: probe = value received by this lane ---
    const int probe = __builtin_amdgcn_mov_dpp(l, ROT_CTRL, 0xf, 0xf, true);
    // receives lower neighbor (l-1) => values move UP => dir = +1
    const int dir = (probe == ((l - 1) & 63)) ? 1 : -1;

    // --- stage Td via LDS (padded transpose: row l = this lane's column) ---
    __shared__ __align__(16) float TdT[L * 68];
    for (int j = 0; j < L; ++j) {
        const float val = trans[j * L + l];          // coalesced
        const int r = (dir * (l - j)) & 63;          // (l - dir*r) & 63 == j
        TdT[l * 68 + r] = val;
    }
    STEP_BARRIER();  // single wave: in-order DS pipe; lane l reads only row l

    f32x4 tdq[16];
#pragma unroll
    for (int k = 0; k < 16; ++k)
        tdq[k] = *reinterpret_cast<const f32x4*>(&TdT[l * 68 + 4 * k]);
    // tdq[k][c] = Td[4k+c][l]

    float vreg = (l == STARTT) ? 0.0f : NEGV;  // v_{-1}

    float fc[4];
#pragma unroll
    for (int j = 0; j < 4; ++j) fc[j] = feats[j * L + l];

    int nextck = 0, cidx = 0;
    for (int tb = 0; tb < TLEN; tb += 4) {   // 200000 % 4 == 0
        if (tb == nextck) {                  // uniform branch
            ckpt[cidx * L + l] = vreg;       // v_{tb-1}, coalesced, off-chain
            nextck += CH;
            ++cidx;
        }
        float fn_[4];
        const bool more = (tb + 4) < TLEN;
        if (more) {
#pragma unroll
            for (int j = 0; j < 4; ++j) fn_[j] = feats[(tb + 4 + j) * L + l];
        }
#pragma unroll
        for (int j = 0; j < 4; ++j) {
            float acc = vreg + tdq[0][1];    // e_1
#pragma unroll
            for (int rr = 2; rr < 65; ++rr) {
                const int r = rr & 63;       // 2..63, then 0 (final alignment n=l)
                acc = fmaxf(rot1(acc), vreg + tdq[r >> 2][r & 3]);
            }
            vreg = acc + fc[j];              // v_t[l]
        }
        if (more) {
#pragma unroll
            for (int j = 0; j < 4; ++j) fc[j] = fn_[j];
        }
    }
    ckpt[NCH * L + l] = vreg;  // v_{T-1}
}

// ---------------------------------------------------------------------------
// helpers for the replay kernels (off the critical path, ~1 ms total)
// ---------------------------------------------------------------------------
__device__ __forceinline__ void load_trow(const float* __restrict__ trans, int n, float* trow) {
#pragma unroll
    for (int i = 0; i < 16; ++i) {
        const f32x4 q = reinterpret_cast<const f32x4*>(trans)[n * 16 + i];
        trow[4 * i + 0] = q.x;
        trow[4 * i + 1] = q.y;
        trow[4 * i + 2] = q.z;
        trow[4 * i + 3] = q.w;
    }
}

// Bit-exact chunk replay from checkpoint; records backpointers into LDS.
// Single wave per block; in-order DS pipe makes ds_write->ds_read safe with
// only a compiler barrier. Argmax is an in-order strictly-greater scan =>
// first-max, matching jnp.argmax; v matches k_forward bit-for-bit (max is
// order-invariant, +feat monotone-exact).
__device__ __forceinline__ void replay_chunk(const float* __restrict__ feats,
                                             const float* __restrict__ ckpt,
                                             const float* trow, float* vsh,
                                             unsigned char* bpl, int c, int len, int n) {
    float vreg = ckpt[c * L + n];
    vsh[n] = vreg;
    STEP_BARRIER();
    const int base = c * CH;

    float fc[8];
#pragma unroll
    for (int j = 0; j < 8; ++j) fc[j] = feats[(base + j) * L + n];

    for (int sb = 0; sb < len; sb += 8) {
        float fn_[8];
        const bool more = (sb + 8) < len;
        if (more) {
#pragma unroll
            for (int j = 0; j < 8; ++j) fn_[j] = feats[(base + sb + 8 + j) * L + n];
        }
#pragma unroll
        for (int j = 0; j < 8; ++j) {
            float mc[4];
            int ic[4];
#pragma unroll
            for (int g = 0; g < 4; ++g) {
                float m = -INFINITY;
                int idx = g * 16;
#pragma unroll
                for (int r = 0; r < 4; ++r) {
                    const int pb = g * 16 + r * 4;
                    const f32x4 vv = *reinterpret_cast<const f32x4*>(vsh + pb);
                    const float a = vv.x + trow[pb + 0];
                    const float b = vv.y + trow[pb + 1];
                    const float cc = vv.z + trow[pb + 2];
                    const float d = vv.w + trow[pb + 3];
                    if (a > m)  { m = a;  idx = pb + 0; }
                    if (b > m)  { m = b;  idx = pb + 1; }
                    if (cc > m) { m = cc; idx = pb + 2; }
                    if (d > m)  { m = d;  idx = pb + 3; }
                }
                mc[g] = m;
                ic[g] = idx;
            }
            float m = mc[0];
            int idx = ic[0];
            if (mc[1] > m) { m = mc[1]; idx = ic[1]; }
            if (mc[2] > m) { m = mc[2]; idx = ic[2]; }
            if (mc[3] > m) { m = mc[3]; idx = ic[3]; }

            vreg = m + fc[j];
            bpl[(sb + j) * L + n] = (unsigned char)idx;
            vsh[n] = vreg;
            STEP_BARRIER();
        }
        if (more) {
#pragma unroll
            for (int j = 0; j < 8; ++j) fc[j] = fn_[j];
        }
    }
}

// ---------------------------------------------------------------------------
// Pass 2: per-chunk bit-exact replay -> backpointers -> 64-entry chunk map.
// M[c*64+e] = tag at (c*CH - 1) given tag e at the last step of chunk c.
// ---------------------------------------------------------------------------
__global__ __launch_bounds__(64, 1) void k_maps(const float* __restrict__ feats,
                                                const float* __restrict__ trans,
                                                const float* __restrict__ ckpt,
                                                unsigned char* __restrict__ M) {
    const int c = blockIdx.x;
    const int n = threadIdx.x;
    const int len = (c == NCH - 1) ? LASTLEN : CH;

    __shared__ __align__(16) float vsh[L];
    __shared__ unsigned char bpl[CH * L];

    float trow[L];
    load_trow(trans, n, trow);
    replay_chunk(feats, ckpt, trow, vsh, bpl, c, len, n);
    __syncthreads();

    int tag = n;
    for (int s = len - 1; s >= 0; --s) tag = bpl[s * L + tag];
    M[c * L + n] = (unsigned char)tag;
}

// ---------------------------------------------------------------------------
// Pass 3: terminal argmax (bit-exact score) + back-to-front map composition.
// ---------------------------------------------------------------------------
__global__ __launch_bounds__(64, 1) void k_stitch(const float* __restrict__ trans,
                                                  const float* __restrict__ ckpt,
                                                  const unsigned char* __restrict__ M,
                                                  int* __restrict__ etag,
                                                  float* __restrict__ out) {
    const int n = threadIdx.x;
    __shared__ float tsh[L];
    __shared__ int bsh;
    __shared__ __align__(16) unsigned char msh[NCH * L];

    tsh[n] = ckpt[NCH * L + n] + trans[STOPT * L + n];  // terminal[n]
    __syncthreads();
    if (n == 0) {
        float m = tsh[0];
        int b = 0;
        for (int p = 1; p < L; ++p)
            if (tsh[p] > m) { m = tsh[p]; b = p; }  // first-max, like jnp.argmax
        out[0] = m;   // path_score, bit-exact
        bsh = b;
    }
    __syncthreads();

    for (int i = n; i < (NCH * L) / 4; i += L)
        reinterpret_cast<int*>(msh)[i] = reinterpret_cast<const int*>(M)[i];
    __syncthreads();

    if (n == 0) {
        int carry = bsh;  // tag at t = T-1 = end of chunk NCH-1
        for (int c = NCH - 1; c >= 1; --c) {
            etag[c] = carry;
            carry = msh[c * L + carry];
        }
        etag[0] = carry;
    }
}

// ---------------------------------------------------------------------------
// Pass 4: per-chunk replay again, walk backwards from etag[c], emit path.
// Path written as float32 (harness reads the concatenated output as float).
// ---------------------------------------------------------------------------
__global__ __launch_bounds__(64, 1) void k_emit(const float* __restrict__ feats,
                                                const float* __restrict__ trans,
                                                const float* __restrict__ ckpt,
                                                const int* __restrict__ etag,
                                                float* __restrict__ out) {
    const int c = blockIdx.x;
    const int n = threadIdx.x;
    const int len = (c == NCH - 1) ? LASTLEN : CH;

    __shared__ __align__(16) float vsh[L];
    __shared__ unsigned char bpl[CH * L];
    __shared__ unsigned char plc[CH];

    float trow[L];
    load_trow(trans, n, trow);
    replay_chunk(feats, ckpt, trow, vsh, bpl, c, len, n);
    __syncthreads();

    int tag = etag[c];  // uniform; bpl reads below broadcast (same address)
    for (int s = len - 1; s >= 0; --s) {
        if (n == 0) plc[s] = (unsigned char)tag;
        tag = bpl[s * L + tag];
    }
    __syncthreads();

    for (int i = n; i < len; i += L)
        out[1 + c * CH + i] = (float)plc[i];
}

// ---------------------------------------------------------------------------
extern "C" void kernel_launch(void* const* d_in, const int* in_sizes, int n_in,
                              void* d_out, int out_size, void* d_ws, size_t ws_size,
                              hipStream_t stream) {
    const float* feats = (const float*)d_in[0];   // (1, T, L) fp32
    const float* trans = (const float*)d_in[1];   // (L, L) fp32
    float* out = (float*)d_out;                   // [score, path(T) as float]
    char* ws = (char*)d_ws;
    float* ckpt = (float*)(ws + CKPT_OFF);
    unsigned char* M = (unsigned char*)(ws + M_OFF);
    int* etag = (int*)(ws + ETAG_OFF);

    hipLaunchKernelGGL(k_forward, dim3(1), dim3(64), 0, stream, feats, trans, ckpt);
    hipLaunchKernelGGL(k_maps, dim3(NCH), dim3(64), 0, stream, feats, trans, ckpt, M);
    hipLaunchKernelGGL(k_stitch, dim3(1), dim3(64), 0, stream, trans, ckpt, M, etag, out);
    hipLaunchKernelGGL(k_emit, dim3(NCH), dim3(64), 0, stream, feats, trans, ckpt, etag, out);
}

// Round 10
// 61957.678 us; speedup vs baseline: 1.9157x; 1.7847x over previous
//
#include <hip/hip_runtime.h>

#define L 64
#define TLEN 200000
#define CH 528                        // divisible by 4 and 8; chunk for replay kernels
#define NCH 379                       // ceil(200000/528); 378*528 = 199584
#define LASTLEN (TLEN - (NCH - 1) * CH)   // 416 (divisible by 8)
#define NEGV -10000.0f
#define STARTT 62
#define STOPT 63

// workspace layout (bytes) — total ~123 KB
#define CKPT_OFF 0                          // float[(NCH+1)*L]  = 97280 B
#define M_OFF ((NCH + 1) * L * 4)           // uchar[NCH*L]      = 24256 B
#define ETAG_OFF (M_OFF + NCH * L)          // int[NCH]          = 1516 B

typedef float f32x4 __attribute__((ext_vector_type(4)));

#define STEP_BARRIER() __asm__ volatile("" ::: "memory")

#define PIN8(a, b, c, d, e, f, g, h)                                          \
    __asm__ volatile("" : "+v"(a), "+v"(b), "+v"(c), "+v"(d),                 \
                          "+v"(e), "+v"(f), "+v"(g), "+v"(h))

static __device__ __forceinline__ f32x4 fmax4(f32x4 a, f32x4 b) {
    f32x4 r;
    r.x = fmaxf(a.x, b.x); r.y = fmaxf(a.y, b.y);
    r.z = fmaxf(a.z, b.z); r.w = fmaxf(a.w, b.w);
    return r;
}

// ---------------------------------------------------------------------------
// Pass 1: exact sequential forward recurrence (the critical path).
// ONE wave, zero barriers in the hot loop.
//
// Round 1's broadcast structure, with the register cap actually fixed:
// every kernel rounds 1-9 was capped at <=72 VGPRs (allocator targets default
// 8 waves/EU = 64-VGPR budget and spills rather than lower occupancy;
// __launch_bounds__'s 2nd arg only RAISES min occupancy). The fix is
// amdgpu_waves_per_eu(1,1): max 1 wave/EU makes the full 512-VGPR budget
// legal, so the 64-float transition row stays resident. The row is staged
// through LDS (ds_read results are not rematerializable — proven in rounds
// 8/9 where tdq stayed pinned) and asm-pinned.
//
// Per step: ds_write_b32 vsh[l]=vreg; 16 uniform-address (broadcast,
// conflict-free) ds_read_b128 of v; f32x4 add + 6-level max tree; +feat.
// Single wave + in-order DS pipe => write->read needs no hardware barrier,
// only compiler ordering (STEP_BARRIER). Bit-exact: each candidate is one
// fp32 add, max is exact/order-invariant, +feat one add.
// ---------------------------------------------------------------------------
__global__ __launch_bounds__(64, 1) __attribute__((amdgpu_waves_per_eu(1, 1)))
void k_forward(const float* __restrict__ feats,
               const float* __restrict__ trans,
               float* __restrict__ ckpt) {
    const int l = threadIdx.x;

    __shared__ __align__(16) float Tsh[L * 68];   // row n at Tsh[n*68], padded
    __shared__ __align__(16) float vsh[L];

    // coalesced global read, conflict-free LDS transpose-store:
    // Tsh[j][l] = T[j][l]  (write banks (4j+l)%32 -> 2-way, free)
    for (int j = 0; j < L; ++j)
        Tsh[j * 68 + l] = trans[j * L + l];
    STEP_BARRIER();  // single wave: in-order DS pipe orders write->read

    // lane l's row T[l][0..63] -> 16 resident quads (one-time 8-way-conflict reads)
    f32x4 tq0  = *reinterpret_cast<const f32x4*>(&Tsh[l * 68 + 0]);
    f32x4 tq1  = *reinterpret_cast<const f32x4*>(&Tsh[l * 68 + 4]);
    f32x4 tq2  = *reinterpret_cast<const f32x4*>(&Tsh[l * 68 + 8]);
    f32x4 tq3  = *reinterpret_cast<const f32x4*>(&Tsh[l * 68 + 12]);
    f32x4 tq4  = *reinterpret_cast<const f32x4*>(&Tsh[l * 68 + 16]);
    f32x4 tq5  = *reinterpret_cast<const f32x4*>(&Tsh[l * 68 + 20]);
    f32x4 tq6  = *reinterpret_cast<const f32x4*>(&Tsh[l * 68 + 24]);
    f32x4 tq7  = *reinterpret_cast<const f32x4*>(&Tsh[l * 68 + 28]);
    f32x4 tq8  = *reinterpret_cast<const f32x4*>(&Tsh[l * 68 + 32]);
    f32x4 tq9  = *reinterpret_cast<const f32x4*>(&Tsh[l * 68 + 36]);
    f32x4 tq10 = *reinterpret_cast<const f32x4*>(&Tsh[l * 68 + 40]);
    f32x4 tq11 = *reinterpret_cast<const f32x4*>(&Tsh[l * 68 + 44]);
    f32x4 tq12 = *reinterpret_cast<const f32x4*>(&Tsh[l * 68 + 48]);
    f32x4 tq13 = *reinterpret_cast<const f32x4*>(&Tsh[l * 68 + 52]);
    f32x4 tq14 = *reinterpret_cast<const f32x4*>(&Tsh[l * 68 + 56]);
    f32x4 tq15 = *reinterpret_cast<const f32x4*>(&Tsh[l * 68 + 60]);
    PIN8(tq0, tq1, tq2, tq3, tq4, tq5, tq6, tq7);
    PIN8(tq8, tq9, tq10, tq11, tq12, tq13, tq14, tq15);

    float vreg = (l == STARTT) ? 0.0f : NEGV;  // v_{-1}

    float fc[4];
#pragma unroll
    for (int j = 0; j < 4; ++j) fc[j] = feats[j * L + l];

#define FWD_STEP(FEAT)                                                        \
    do {                                                                      \
        vsh[l] = vreg;                                                        \
        STEP_BARRIER();                                                       \
        const f32x4 c0  = *reinterpret_cast<const f32x4*>(&vsh[0])  + tq0;    \
        const f32x4 c1  = *reinterpret_cast<const f32x4*>(&vsh[4])  + tq1;    \
        const f32x4 c2  = *reinterpret_cast<const f32x4*>(&vsh[8])  + tq2;    \
        const f32x4 c3  = *reinterpret_cast<const f32x4*>(&vsh[12]) + tq3;    \
        const f32x4 c4  = *reinterpret_cast<const f32x4*>(&vsh[16]) + tq4;    \
        const f32x4 c5  = *reinterpret_cast<const f32x4*>(&vsh[20]) + tq5;    \
        const f32x4 c6  = *reinterpret_cast<const f32x4*>(&vsh[24]) + tq6;    \
        const f32x4 c7  = *reinterpret_cast<const f32x4*>(&vsh[28]) + tq7;    \
        const f32x4 c8  = *reinterpret_cast<const f32x4*>(&vsh[32]) + tq8;    \
        const f32x4 c9  = *reinterpret_cast<const f32x4*>(&vsh[36]) + tq9;    \
        const f32x4 c10 = *reinterpret_cast<const f32x4*>(&vsh[40]) + tq10;   \
        const f32x4 c11 = *reinterpret_cast<const f32x4*>(&vsh[44]) + tq11;   \
        const f32x4 c12 = *reinterpret_cast<const f32x4*>(&vsh[48]) + tq12;   \
        const f32x4 c13 = *reinterpret_cast<const f32x4*>(&vsh[52]) + tq13;   \
        const f32x4 c14 = *reinterpret_cast<const f32x4*>(&vsh[56]) + tq14;   \
        const f32x4 c15 = *reinterpret_cast<const f32x4*>(&vsh[60]) + tq15;   \
        const f32x4 d0 = fmax4(c0, c1),  d1 = fmax4(c2, c3);                  \
        const f32x4 d2 = fmax4(c4, c5),  d3 = fmax4(c6, c7);                  \
        const f32x4 d4 = fmax4(c8, c9),  d5 = fmax4(c10, c11);                \
        const f32x4 d6 = fmax4(c12, c13), d7 = fmax4(c14, c15);               \
        const f32x4 e0 = fmax4(d0, d1), e1 = fmax4(d2, d3);                   \
        const f32x4 e2 = fmax4(d4, d5), e3 = fmax4(d6, d7);                   \
        const f32x4 g = fmax4(fmax4(e0, e1), fmax4(e2, e3));                  \
        const float m = fmaxf(fmaxf(g.x, g.y), fmaxf(g.z, g.w));              \
        vreg = m + (FEAT);                                                    \
        STEP_BARRIER();                                                       \
    } while (0)

    int nextck = 0, cidx = 0;
    for (int tb = 0; tb < TLEN; tb += 4) {   // 200000 % 4 == 0
        if (tb == nextck) {                  // uniform branch
            ckpt[cidx * L + l] = vreg;       // v_{tb-1}, coalesced, off-chain
            nextck += CH;
            ++cidx;
        }
        float fn_[4];
        const bool more = (tb + 4) < TLEN;
        if (more) {
#pragma unroll
            for (int j = 0; j < 4; ++j) fn_[j] = feats[(tb + 4 + j) * L + l];
        }
        FWD_STEP(fc[0]);
        FWD_STEP(fc[1]);
        FWD_STEP(fc[2]);
        FWD_STEP(fc[3]);
        if (more) {
#pragma unroll
            for (int j = 0; j < 4; ++j) fc[j] = fn_[j];
        }
    }
    ckpt[NCH * L + l] = vreg;  // v_{T-1}
#undef FWD_STEP
}

// ---------------------------------------------------------------------------
// helpers for the replay kernels (off the critical path, ~1 ms total)
// ---------------------------------------------------------------------------
__device__ __forceinline__ void load_trow(const float* __restrict__ trans, int n, float* trow) {
#pragma unroll
    for (int i = 0; i < 16; ++i) {
        const f32x4 q = reinterpret_cast<const f32x4*>(trans)[n * 16 + i];
        trow[4 * i + 0] = q.x;
        trow[4 * i + 1] = q.y;
        trow[4 * i + 2] = q.z;
        trow[4 * i + 3] = q.w;
    }
}

// Bit-exact chunk replay from checkpoint; records backpointers into LDS.
// Single wave per block; in-order DS pipe makes ds_write->ds_read safe with
// only a compiler barrier. Argmax is an in-order strictly-greater scan =>
// first-max, matching jnp.argmax; v matches k_forward bit-for-bit (max is
// order-invariant, +feat monotone-exact).
__device__ __forceinline__ void replay_chunk(const float* __restrict__ feats,
                                             const float* __restrict__ ckpt,
                                             const float* trow, float* vsh,
                                             unsigned char* bpl, int c, int len, int n) {
    float vreg = ckpt[c * L + n];
    vsh[n] = vreg;
    STEP_BARRIER();
    const int base = c * CH;

    float fc[8];
#pragma unroll
    for (int j = 0; j < 8; ++j) fc[j] = feats[(base + j) * L + n];

    for (int sb = 0; sb < len; sb += 8) {
        float fn_[8];
        const bool more = (sb + 8) < len;
        if (more) {
#pragma unroll
            for (int j = 0; j < 8; ++j) fn_[j] = feats[(base + sb + 8 + j) * L + n];
        }
#pragma unroll
        for (int j = 0; j < 8; ++j) {
            float mc[4];
            int ic[4];
#pragma unroll
            for (int g = 0; g < 4; ++g) {
                float m = -INFINITY;
                int idx = g * 16;
#pragma unroll
                for (int r = 0; r < 4; ++r) {
                    const int pb = g * 16 + r * 4;
                    const f32x4 vv = *reinterpret_cast<const f32x4*>(vsh + pb);
                    const float a = vv.x + trow[pb + 0];
                    const float b = vv.y + trow[pb + 1];
                    const float cc = vv.z + trow[pb + 2];
                    const float d = vv.w + trow[pb + 3];
                    if (a > m)  { m = a;  idx = pb + 0; }
                    if (b > m)  { m = b;  idx = pb + 1; }
                    if (cc > m) { m = cc; idx = pb + 2; }
                    if (d > m)  { m = d;  idx = pb + 3; }
                }
                mc[g] = m;
                ic[g] = idx;
            }
            float m = mc[0];
            int idx = ic[0];
            if (mc[1] > m) { m = mc[1]; idx = ic[1]; }
            if (mc[2] > m) { m = mc[2]; idx = ic[2]; }
            if (mc[3] > m) { m = mc[3]; idx = ic[3]; }

            vreg = m + fc[j];
            bpl[(sb + j) * L + n] = (unsigned char)idx;
            vsh[n] = vreg;
            STEP_BARRIER();
        }
        if (more) {
#pragma unroll
            for (int j = 0; j < 8; ++j) fc[j] = fn_[j];
        }
    }
}

// ---------------------------------------------------------------------------
// Pass 2: per-chunk bit-exact replay -> backpointers -> 64-entry chunk map.
// M[c*64+e] = tag at (c*CH - 1) given tag e at the last step of chunk c.
// ---------------------------------------------------------------------------
__global__ __launch_bounds__(64, 1) __attribute__((amdgpu_waves_per_eu(1, 1)))
void k_maps(const float* __restrict__ feats,
            const float* __restrict__ trans,
            const float* __restrict__ ckpt,
            unsigned char* __restrict__ M) {
    const int c = blockIdx.x;
    const int n = threadIdx.x;
    const int len = (c == NCH - 1) ? LASTLEN : CH;

    __shared__ __align__(16) float vsh[L];
    __shared__ unsigned char bpl[CH * L];

    float trow[L];
    load_trow(trans, n, trow);
    replay_chunk(feats, ckpt, trow, vsh, bpl, c, len, n);
    __syncthreads();

    int tag = n;
    for (int s = len - 1; s >= 0; --s) tag = bpl[s * L + tag];
    M[c * L + n] = (unsigned char)tag;
}

// ---------------------------------------------------------------------------
// Pass 3: terminal argmax (bit-exact score) + back-to-front map composition.
// ---------------------------------------------------------------------------
__global__ __launch_bounds__(64, 1) void k_stitch(const float* __restrict__ trans,
                                                  const float* __restrict__ ckpt,
                                                  const unsigned char* __restrict__ M,
                                                  int* __restrict__ etag,
                                                  float* __restrict__ out) {
    const int n = threadIdx.x;
    __shared__ float tsh[L];
    __shared__ int bsh;
    __shared__ __align__(16) unsigned char msh[NCH * L];

    tsh[n] = ckpt[NCH * L + n] + trans[STOPT * L + n];  // terminal[n]
    __syncthreads();
    if (n == 0) {
        float m = tsh[0];
        int b = 0;
        for (int p = 1; p < L; ++p)
            if (tsh[p] > m) { m = tsh[p]; b = p; }  // first-max, like jnp.argmax
        out[0] = m;   // path_score, bit-exact
        bsh = b;
    }
    __syncthreads();

    for (int i = n; i < (NCH * L) / 4; i += L)
        reinterpret_cast<int*>(msh)[i] = reinterpret_cast<const int*>(M)[i];
    __syncthreads();

    if (n == 0) {
        int carry = bsh;  // tag at t = T-1 = end of chunk NCH-1
        for (int c = NCH - 1; c >= 1; --c) {
            etag[c] = carry;
            carry = msh[c * L + carry];
        }
        etag[0] = carry;
    }
}

// ---------------------------------------------------------------------------
// Pass 4: per-chunk replay again, walk backwards from etag[c], emit path.
// Path written as float32 (harness reads the concatenated output as float).
// ---------------------------------------------------------------------------
__global__ __launch_bounds__(64, 1) __attribute__((amdgpu_waves_per_eu(1, 1)))
void k_emit(const float* __restrict__ feats,
            const float* __restrict__ trans,
            const float* __restrict__ ckpt,
            const int* __restrict__ etag,
            float* __restrict__ out) {
    const int c = blockIdx.x;
    const int n = threadIdx.x;
    const int len = (c == NCH - 1) ? LASTLEN : CH;

    __shared__ __align__(16) float vsh[L];
    __shared__ unsigned char bpl[CH * L];
    __shared__ unsigned char plc[CH];

    float trow[L];
    load_trow(trans, n, trow);
    replay_chunk(feats, ckpt, trow, vsh, bpl, c, len, n);
    __syncthreads();

    int tag = etag[c];  // uniform; bpl reads below broadcast (same address)
    for (int s = len - 1; s >= 0; --s) {
        if (n == 0) plc[s] = (unsigned char)tag;
        tag = bpl[s * L + tag];
    }
    __syncthreads();

    for (int i = n; i < len; i += L)
        out[1 + c * CH + i] = (float)plc[i];
}

// ---------------------------------------------------------------------------
extern "C" void kernel_launch(void* const* d_in, const int* in_sizes, int n_in,
                              void* d_out, int out_size, void* d_ws, size_t ws_size,
                              hipStream_t stream) {
    const float* feats = (const float*)d_in[0];   // (1, T, L) fp32
    const float* trans = (const float*)d_in[1];   // (L, L) fp32
    float* out = (float*)d_out;                   // [score, path(T) as float]
    char* ws = (char*)d_ws;
    float* ckpt = (float*)(ws + CKPT_OFF);
    unsigned char* M = (unsigned char*)(ws + M_OFF);
    int* etag = (int*)(ws + ETAG_OFF);

    hipLaunchKernelGGL(k_forward, dim3(1), dim3(64), 0, stream, feats, trans, ckpt);
    hipLaunchKernelGGL(k_maps, dim3(NCH), dim3(64), 0, stream, feats, trans, ckpt, M);
    hipLaunchKernelGGL(k_stitch, dim3(1), dim3(64), 0, stream, trans, ckpt, M, etag, out);
    hipLaunchKernelGGL(k_emit, dim3(NCH), dim3(64), 0, stream, feats, trans, ckpt, etag, out);
}